// Round 1
// baseline (486.693 us; speedup 1.0000x reference)
//
#include <hip/hip_runtime.h>

#define N_NODES 50000
#define N_EDGES 800000
#define D_IN    256
#define D_H     64
#define D_OUT   40

// ---------------- degree + norm ----------------

__global__ void deg_kernel(const int* __restrict__ src, const int* __restrict__ dst,
                           float* __restrict__ deg_out, float* __restrict__ deg_in) {
    int e = blockIdx.x * blockDim.x + threadIdx.x;
    if (e < N_EDGES) {
        atomicAdd(&deg_out[src[e]], 1.0f);
        atomicAdd(&deg_in[dst[e]], 1.0f);
    }
}

__global__ void norm_kernel(const float* __restrict__ deg_out, const float* __restrict__ deg_in,
                            float* __restrict__ norm_out, float* __restrict__ norm_in) {
    int i = blockIdx.x * blockDim.x + threadIdx.x;
    if (i < N_NODES) {
        norm_out[i] = rsqrtf(fmaxf(deg_out[i], 1.0f));
        norm_in[i]  = rsqrtf(fmaxf(deg_in[i], 1.0f));
    }
}

// ---------------- GEMM1: h1[n][j] = norm_out[n] * dot(feat[n,:], W1[:,j]) ----------------
// 4 waves per block; wave w owns k in [w*64, w*64+64); thread lane j holds W1[k][j]
// for its 64 k's in VGPRs. feat row chunk read via wave-uniform scalar loads.

__global__ void __launch_bounds__(256) gemm1_kernel(const float* __restrict__ feat,
                                                    const float* __restrict__ W1,
                                                    const float* __restrict__ norm_out,
                                                    float* __restrict__ h1) {
    const int j = threadIdx.x & 63;
    const int w = threadIdx.x >> 6;

    float wreg[64];
#pragma unroll
    for (int kk = 0; kk < 64; ++kk)
        wreg[kk] = W1[(w * 64 + kk) * D_H + j];

    __shared__ float part[4][64];

    for (int n = blockIdx.x; n < N_NODES; n += gridDim.x) {
        int off = __builtin_amdgcn_readfirstlane(n * D_IN + w * 64);
        const float* fp = feat + off;
        float acc = 0.0f;
#pragma unroll
        for (int kk = 0; kk < 64; ++kk)
            acc = fmaf(fp[kk], wreg[kk], acc);
        part[w][j] = acc;
        __syncthreads();
        if (w == 0) {
            float v = (part[0][j] + part[1][j] + part[2][j] + part[3][j]) * norm_out[n];
            h1[n * D_H + j] = v;
        }
        __syncthreads();
    }
}

// ---------------- edge scatter, layer 1: agg1[dst] += h1[src], 64 dims, wave per edge ----------------

__global__ void __launch_bounds__(256) edge1_kernel(const int* __restrict__ src,
                                                    const int* __restrict__ dst,
                                                    const float* __restrict__ h1,
                                                    float* __restrict__ agg1) {
    int e = (int)(blockIdx.x * 4u) + (threadIdx.x >> 6);
    e = __builtin_amdgcn_readfirstlane(e);
    const int j = threadIdx.x & 63;
    if (e < N_EDGES) {
        int s = src[e];
        int d = dst[e];
        float v = h1[s * D_H + j];
        atomicAdd(&agg1[d * D_H + j], v);
    }
}

// ---------------- post layer 1: g = relu(agg1*norm_in + b1) * norm_out ----------------

__global__ void post1_kernel(const float* __restrict__ agg1,
                             const float* __restrict__ norm_in,
                             const float* __restrict__ norm_out,
                             const float* __restrict__ b1,
                             float* __restrict__ g) {
    int i = blockIdx.x * blockDim.x + threadIdx.x;
    if (i < N_NODES * D_H) {
        int n = i >> 6, j = i & 63;
        float v = fmaf(agg1[i], norm_in[n], b1[j]);
        v = fmaxf(v, 0.0f);
        g[i] = v * norm_out[n];
    }
}

// ---------------- GEMM2: h2[n][j] = dot(g[n,:64], W2[:,j]), wave per node ----------------

__global__ void __launch_bounds__(256) gemm2_kernel(const float* __restrict__ g,
                                                    const float* __restrict__ W2,
                                                    float* __restrict__ h2) {
    const int j = threadIdx.x & 63;
    const int wave = (int)((blockIdx.x * blockDim.x + threadIdx.x) >> 6);
    const int nwaves = (int)((gridDim.x * blockDim.x) >> 6);

    float wreg[64];
#pragma unroll
    for (int kk = 0; kk < 64; ++kk)
        wreg[kk] = (j < D_OUT) ? W2[kk * D_OUT + j] : 0.0f;

    for (int n = wave; n < N_NODES; n += nwaves) {
        int off = __builtin_amdgcn_readfirstlane(n * D_H);
        const float* gp = g + off;
        float acc = 0.0f;
#pragma unroll
        for (int kk = 0; kk < 64; ++kk)
            acc = fmaf(gp[kk], wreg[kk], acc);
        if (j < D_OUT)
            h2[n * D_OUT + j] = acc;
    }
}

// ---------------- edge scatter, layer 2: out[dst] += h2[src], 40 dims, wave per edge ----------------

__global__ void __launch_bounds__(256) edge2_kernel(const int* __restrict__ src,
                                                    const int* __restrict__ dst,
                                                    const float* __restrict__ h2,
                                                    float* __restrict__ out) {
    int e = (int)(blockIdx.x * 4u) + (threadIdx.x >> 6);
    e = __builtin_amdgcn_readfirstlane(e);
    const int j = threadIdx.x & 63;
    if (e < N_EDGES && j < D_OUT) {
        int s = src[e];
        int d = dst[e];
        float v = h2[s * D_OUT + j];
        atomicAdd(&out[d * D_OUT + j], v);
    }
}

// ---------------- final: out = out*norm_in + b2 (in place) ----------------

__global__ void final_kernel(float* __restrict__ out,
                             const float* __restrict__ norm_in,
                             const float* __restrict__ b2) {
    int i = blockIdx.x * blockDim.x + threadIdx.x;
    if (i < N_NODES * D_OUT) {
        unsigned n = (unsigned)i / D_OUT;
        unsigned j = (unsigned)i - n * D_OUT;
        out[i] = fmaf(out[i], norm_in[n], b2[j]);
    }
}

extern "C" void kernel_launch(void* const* d_in, const int* in_sizes, int n_in,
                              void* d_out, int out_size, void* d_ws, size_t ws_size,
                              hipStream_t stream) {
    const float* feat = (const float*)d_in[0];
    const int*   src  = (const int*)d_in[1];
    const int*   dst  = (const int*)d_in[2];
    const float* W1   = (const float*)d_in[3];
    const float* b1   = (const float*)d_in[4];
    const float* W2   = (const float*)d_in[5];
    const float* b2   = (const float*)d_in[6];
    float* out = (float*)d_out;

    float* ws       = (float*)d_ws;
    float* deg_out  = ws;                       // N
    float* deg_in   = ws + N_NODES;             // N   (contiguous with deg_out for one memset)
    float* norm_out = ws + 2 * N_NODES;         // N
    float* norm_in  = ws + 3 * N_NODES;         // N
    float* h1       = ws + 4 * N_NODES;         // N*64  (reused as g after post1)
    float* agg1     = h1 + (size_t)N_NODES * D_H;     // N*64
    float* h2       = agg1 + (size_t)N_NODES * D_H;   // N*40

    hipMemsetAsync(deg_out, 0, 2u * N_NODES * sizeof(float), stream);
    hipMemsetAsync(agg1, 0, (size_t)N_NODES * D_H * sizeof(float), stream);
    hipMemsetAsync(out, 0, (size_t)N_NODES * D_OUT * sizeof(float), stream);

    deg_kernel<<<(N_EDGES + 255) / 256, 256, 0, stream>>>(src, dst, deg_out, deg_in);
    norm_kernel<<<(N_NODES + 255) / 256, 256, 0, stream>>>(deg_out, deg_in, norm_out, norm_in);

    gemm1_kernel<<<2048, 256, 0, stream>>>(feat, W1, norm_out, h1);
    edge1_kernel<<<N_EDGES / 4, 256, 0, stream>>>(src, dst, h1, agg1);
    post1_kernel<<<(N_NODES * D_H + 255) / 256, 256, 0, stream>>>(agg1, norm_in, norm_out, b1, h1);

    gemm2_kernel<<<1024, 256, 0, stream>>>(h1, W2, h2);
    edge2_kernel<<<N_EDGES / 4, 256, 0, stream>>>(src, dst, h2, out);
    final_kernel<<<(N_NODES * D_OUT + 255) / 256, 256, 0, stream>>>(out, norm_in, b2);
}

// Round 2
// 326.678 us; speedup vs baseline: 1.4898x; 1.4898x over previous
//
#include <hip/hip_runtime.h>

#define N_NODES 50000
#define N_EDGES 800000
#define D_IN    256
#define D_H     64
#define D_OUT   40

// ---------------- degree histogram (int) ----------------

__global__ void hist_kernel(const int* __restrict__ src, const int* __restrict__ dst,
                            int* __restrict__ cnt_out, int* __restrict__ cnt_in) {
    int e = blockIdx.x * blockDim.x + threadIdx.x;
    if (e < N_EDGES) {
        atomicAdd(&cnt_out[src[e]], 1);
        atomicAdd(&cnt_in[dst[e]], 1);
    }
}

__global__ void norm_kernel(const int* __restrict__ cnt_out, const int* __restrict__ cnt_in,
                            float* __restrict__ norm_out, float* __restrict__ norm_in) {
    int i = blockIdx.x * blockDim.x + threadIdx.x;
    if (i < N_NODES) {
        norm_out[i] = rsqrtf(fmaxf((float)cnt_out[i], 1.0f));
        norm_in[i]  = rsqrtf(fmaxf((float)cnt_in[i], 1.0f));
    }
}

// ---------------- exclusive scan of cnt_in -> start[] (CSR row pointers) ----------------

#define SCAN_NB ((N_NODES + 255) / 256)   // 196

__global__ void scan1_kernel(const int* __restrict__ cnt, int* __restrict__ start,
                             int* __restrict__ blocksum) {
    __shared__ int tmp[256];
    int i = blockIdx.x * 256 + threadIdx.x;
    int v = (i < N_NODES) ? cnt[i] : 0;
    tmp[threadIdx.x] = v;
    __syncthreads();
    for (int off = 1; off < 256; off <<= 1) {
        int t = (threadIdx.x >= off) ? tmp[threadIdx.x - off] : 0;
        __syncthreads();
        tmp[threadIdx.x] += t;
        __syncthreads();
    }
    if (i < N_NODES) start[i] = tmp[threadIdx.x] - v;      // exclusive within block
    if (threadIdx.x == 255) blocksum[blockIdx.x] = tmp[255];
}

__global__ void scan2_kernel(int* __restrict__ blocksum) {
    __shared__ int tmp[256];
    int v = (threadIdx.x < SCAN_NB) ? blocksum[threadIdx.x] : 0;
    tmp[threadIdx.x] = v;
    __syncthreads();
    for (int off = 1; off < 256; off <<= 1) {
        int t = (threadIdx.x >= off) ? tmp[threadIdx.x - off] : 0;
        __syncthreads();
        tmp[threadIdx.x] += t;
        __syncthreads();
    }
    blocksum[threadIdx.x] = tmp[threadIdx.x] - v;          // exclusive block offsets
}

__global__ void scan3_kernel(int* __restrict__ start, const int* __restrict__ blocksum) {
    int i = blockIdx.x * 256 + threadIdx.x;
    if (i < N_NODES) start[i] += blocksum[i >> 8];
    if (i == 0) start[N_NODES] = N_EDGES;
}

// ---------------- scatter edges into CSR order ----------------

__global__ void scatter_kernel(const int* __restrict__ src, const int* __restrict__ dst,
                               const int* __restrict__ start, int* __restrict__ cursor,
                               int* __restrict__ ssrc) {
    int e = blockIdx.x * blockDim.x + threadIdx.x;
    if (e < N_EDGES) {
        int d = dst[e];
        int pos = start[d] + atomicAdd(&cursor[d], 1);
        ssrc[pos] = src[e];
    }
}

// ---------------- GEMM1: h1[n][j] = norm_out[n] * dot(feat[n,:], W1[:,j]) ----------------

__global__ void __launch_bounds__(256) gemm1_kernel(const float* __restrict__ feat,
                                                    const float* __restrict__ W1,
                                                    const float* __restrict__ norm_out,
                                                    float* __restrict__ h1) {
    const int j = threadIdx.x & 63;
    const int w = threadIdx.x >> 6;

    float wreg[64];
#pragma unroll
    for (int kk = 0; kk < 64; ++kk)
        wreg[kk] = W1[(w * 64 + kk) * D_H + j];

    __shared__ float part[4][64];

    for (int n = blockIdx.x; n < N_NODES; n += gridDim.x) {
        int off = __builtin_amdgcn_readfirstlane(n * D_IN + w * 64);
        const float* fp = feat + off;
        float acc = 0.0f;
#pragma unroll
        for (int kk = 0; kk < 64; ++kk)
            acc = fmaf(fp[kk], wreg[kk], acc);
        part[w][j] = acc;
        __syncthreads();
        if (w == 0) {
            float v = (part[0][j] + part[1][j] + part[2][j] + part[3][j]) * norm_out[n];
            h1[n * D_H + j] = v;
        }
        __syncthreads();
    }
}

// ---------------- agg1: g[n][j] = relu(sum_{e in CSR[n]} h1[ssrc[e]][j] * norm_in[n] + b1[j]) * norm_out[n] ----------------

__global__ void __launch_bounds__(256) agg1_kernel(const int* __restrict__ start,
                                                   const int* __restrict__ ssrc,
                                                   const float* __restrict__ h1,
                                                   const float* __restrict__ norm_in,
                                                   const float* __restrict__ norm_out,
                                                   const float* __restrict__ b1,
                                                   float* __restrict__ g) {
    const int j = threadIdx.x & 63;
    const int wave = (int)((blockIdx.x * blockDim.x + threadIdx.x) >> 6);
    const int nwaves = (int)((gridDim.x * blockDim.x) >> 6);
    const float bj = b1[j];

    for (int n = wave; n < N_NODES; n += nwaves) {
        int beg = __builtin_amdgcn_readfirstlane(start[n]);
        int end = __builtin_amdgcn_readfirstlane(start[n + 1]);
        float acc = 0.0f;
        for (int e = beg; e < end; ++e) {
            int s = __builtin_amdgcn_readfirstlane(ssrc[e]);
            acc += h1[s * D_H + j];
        }
        float v = fmaf(acc, norm_in[n], bj);
        v = fmaxf(v, 0.0f) * norm_out[n];
        g[n * D_H + j] = v;
    }
}

// ---------------- GEMM2: h2[n][j] = dot(g[n,:64], W2[:,j]) ----------------

__global__ void __launch_bounds__(256) gemm2_kernel(const float* __restrict__ g,
                                                    const float* __restrict__ W2,
                                                    float* __restrict__ h2) {
    const int j = threadIdx.x & 63;
    const int wave = (int)((blockIdx.x * blockDim.x + threadIdx.x) >> 6);
    const int nwaves = (int)((gridDim.x * blockDim.x) >> 6);

    float wreg[64];
#pragma unroll
    for (int kk = 0; kk < 64; ++kk)
        wreg[kk] = (j < D_OUT) ? W2[kk * D_OUT + j] : 0.0f;

    for (int n = wave; n < N_NODES; n += nwaves) {
        int off = __builtin_amdgcn_readfirstlane(n * D_H);
        const float* gp = g + off;
        float acc = 0.0f;
#pragma unroll
        for (int kk = 0; kk < 64; ++kk)
            acc = fmaf(gp[kk], wreg[kk], acc);
        if (j < D_OUT)
            h2[n * D_OUT + j] = acc;
    }
}

// ---------------- agg2: out[n][j] = (sum_{e in CSR[n]} h2[ssrc[e]][j]) * norm_in[n] + b2[j] ----------------

__global__ void __launch_bounds__(256) agg2_kernel(const int* __restrict__ start,
                                                   const int* __restrict__ ssrc,
                                                   const float* __restrict__ h2,
                                                   const float* __restrict__ norm_in,
                                                   const float* __restrict__ b2,
                                                   float* __restrict__ out) {
    const int j = threadIdx.x & 63;
    const int wave = (int)((blockIdx.x * blockDim.x + threadIdx.x) >> 6);
    const int nwaves = (int)((gridDim.x * blockDim.x) >> 6);
    const float bj = (j < D_OUT) ? b2[j] : 0.0f;

    for (int n = wave; n < N_NODES; n += nwaves) {
        int beg = __builtin_amdgcn_readfirstlane(start[n]);
        int end = __builtin_amdgcn_readfirstlane(start[n + 1]);
        float acc = 0.0f;
        for (int e = beg; e < end; ++e) {
            int s = __builtin_amdgcn_readfirstlane(ssrc[e]);
            if (j < D_OUT) acc += h2[s * D_OUT + j];
        }
        if (j < D_OUT)
            out[n * D_OUT + j] = fmaf(acc, norm_in[n], bj);
    }
}

extern "C" void kernel_launch(void* const* d_in, const int* in_sizes, int n_in,
                              void* d_out, int out_size, void* d_ws, size_t ws_size,
                              hipStream_t stream) {
    const float* feat = (const float*)d_in[0];
    const int*   src  = (const int*)d_in[1];
    const int*   dst  = (const int*)d_in[2];
    const float* W1   = (const float*)d_in[3];
    const float* b1   = (const float*)d_in[4];
    const float* W2   = (const float*)d_in[5];
    const float* b2   = (const float*)d_in[6];
    float* out = (float*)d_out;

    char* base = (char*)d_ws;
    int*   cnt_out  = (int*)base;                       base += N_NODES * 4;
    int*   cnt_in   = (int*)base;                       base += N_NODES * 4;
    int*   cursor   = (int*)base;                       base += N_NODES * 4;
    int*   start    = (int*)base;                       base += (N_NODES + 1) * 4;
    int*   blocksum = (int*)base;                       base += 256 * 4;
    float* norm_out = (float*)base;                     base += N_NODES * 4;
    float* norm_in  = (float*)base;                     base += N_NODES * 4;
    int*   ssrc     = (int*)base;                       base += N_EDGES * 4;
    float* h1       = (float*)base;                     base += (size_t)N_NODES * D_H * 4;
    float* g        = (float*)base;                     base += (size_t)N_NODES * D_H * 4;
    float* h2       = (float*)base;                     base += (size_t)N_NODES * D_OUT * 4;

    // zero cnt_out, cnt_in, cursor (contiguous)
    hipMemsetAsync(cnt_out, 0, 3u * N_NODES * 4, stream);

    hist_kernel<<<(N_EDGES + 255) / 256, 256, 0, stream>>>(src, dst, cnt_out, cnt_in);
    norm_kernel<<<(N_NODES + 255) / 256, 256, 0, stream>>>(cnt_out, cnt_in, norm_out, norm_in);

    scan1_kernel<<<SCAN_NB, 256, 0, stream>>>(cnt_in, start, blocksum);
    scan2_kernel<<<1, 256, 0, stream>>>(blocksum);
    scan3_kernel<<<SCAN_NB, 256, 0, stream>>>(start, blocksum);
    scatter_kernel<<<(N_EDGES + 255) / 256, 256, 0, stream>>>(src, dst, start, cursor, ssrc);

    gemm1_kernel<<<2048, 256, 0, stream>>>(feat, W1, norm_out, h1);
    agg1_kernel<<<1563, 256, 0, stream>>>(start, ssrc, h1, norm_in, norm_out, b1, g);

    gemm2_kernel<<<1024, 256, 0, stream>>>(g, W2, h2);
    agg2_kernel<<<1563, 256, 0, stream>>>(start, ssrc, h2, norm_in, b2, out);
}

// Round 3
// 283.629 us; speedup vs baseline: 1.7160x; 1.1518x over previous
//
#include <hip/hip_runtime.h>
#include <stdint.h>

#define N_NODES 50000
#define N_EDGES 800000
#define D_IN    256
#define D_H     64
#define D_O     40
#define D_OP    48   // h2 padded row stride

// ---------------- degree histogram (int) ----------------

__global__ void hist_kernel(const int* __restrict__ src, const int* __restrict__ dst,
                            int* __restrict__ cnt_out, int* __restrict__ cnt_in) {
    int e = blockIdx.x * blockDim.x + threadIdx.x;
    if (e < N_EDGES) {
        atomicAdd(&cnt_out[src[e]], 1);
        atomicAdd(&cnt_in[dst[e]], 1);
    }
}

__global__ void norm_kernel(const int* __restrict__ cnt_out, const int* __restrict__ cnt_in,
                            float* __restrict__ norm_out, float* __restrict__ norm_in) {
    int i = blockIdx.x * blockDim.x + threadIdx.x;
    if (i < N_NODES) {
        norm_out[i] = rsqrtf(fmaxf((float)cnt_out[i], 1.0f));
        norm_in[i]  = rsqrtf(fmaxf((float)cnt_in[i], 1.0f));
    }
}

// ---------------- exclusive scan of cnt_in -> start[] ----------------

#define SCAN_NB ((N_NODES + 255) / 256)   // 196

__global__ void scan1_kernel(const int* __restrict__ cnt, int* __restrict__ start,
                             int* __restrict__ blocksum) {
    __shared__ int tmp[256];
    int i = blockIdx.x * 256 + threadIdx.x;
    int v = (i < N_NODES) ? cnt[i] : 0;
    tmp[threadIdx.x] = v;
    __syncthreads();
    for (int off = 1; off < 256; off <<= 1) {
        int t = (threadIdx.x >= off) ? tmp[threadIdx.x - off] : 0;
        __syncthreads();
        tmp[threadIdx.x] += t;
        __syncthreads();
    }
    if (i < N_NODES) start[i] = tmp[threadIdx.x] - v;
    if (threadIdx.x == 255) blocksum[blockIdx.x] = tmp[255];
}

__global__ void scan2_kernel(int* __restrict__ blocksum) {
    __shared__ int tmp[256];
    int v = (threadIdx.x < SCAN_NB) ? blocksum[threadIdx.x] : 0;
    tmp[threadIdx.x] = v;
    __syncthreads();
    for (int off = 1; off < 256; off <<= 1) {
        int t = (threadIdx.x >= off) ? tmp[threadIdx.x - off] : 0;
        __syncthreads();
        tmp[threadIdx.x] += t;
        __syncthreads();
    }
    blocksum[threadIdx.x] = tmp[threadIdx.x] - v;
}

__global__ void scan3_kernel(int* __restrict__ start, const int* __restrict__ blocksum) {
    int i = blockIdx.x * 256 + threadIdx.x;
    if (i < N_NODES) start[i] += blocksum[i >> 8];
    if (i == 0) start[N_NODES] = N_EDGES;
}

// ---------------- scatter edges into CSR order ----------------

__global__ void scatter_kernel(const int* __restrict__ src, const int* __restrict__ dst,
                               const int* __restrict__ start, int* __restrict__ cursor,
                               int* __restrict__ ssrc) {
    int e = blockIdx.x * blockDim.x + threadIdx.x;
    if (e < N_EDGES) {
        int d = dst[e];
        int pos = start[d] + atomicAdd(&cursor[d], 1);
        ssrc[pos] = src[e];
    }
}

// ---------------- GEMM1: h1[n][j] = norm_out[n] * dot(feat[n,:], W1[:,j]) ----------------
// 4 waves/block, wave w owns k-slice [w*64, w*64+64); W1 slice in 64 VGPRs/thread.
// __launch_bounds__(256,4): VGPR cap 128 so wreg[64] stays register-resident.
// 4 rows per iteration: 4 independent scalar-load streams, barriers amortized.

__global__ void __launch_bounds__(256, 4) gemm1_kernel(const float* __restrict__ feat,
                                                       const float* __restrict__ W1,
                                                       const float* __restrict__ norm_out,
                                                       float* __restrict__ h1) {
    const int j = threadIdx.x & 63;
    const int w = threadIdx.x >> 6;

    float wreg[64];
#pragma unroll
    for (int kk = 0; kk < 64; ++kk)
        wreg[kk] = W1[(w * 64 + kk) * D_H + j];

    __shared__ float part[4][4][64];   // [row][wave][j]

    const int step = gridDim.x * 4;
    for (int r0 = blockIdx.x * 4; r0 < N_NODES; r0 += step) {
        float acc[4];
#pragma unroll
        for (int r = 0; r < 4; ++r) {
            int n = r0 + r;
            float a = 0.0f;
            if (n < N_NODES) {
                int off = __builtin_amdgcn_readfirstlane(n * D_IN + w * 64);
                const float* fp = feat + off;
#pragma unroll
                for (int kk = 0; kk < 64; ++kk)
                    a = fmaf(fp[kk], wreg[kk], a);
            }
            acc[r] = a;
        }
        __syncthreads();   // part free from previous iteration
#pragma unroll
        for (int r = 0; r < 4; ++r)
            part[r][w][j] = acc[r];
        __syncthreads();
        int n = r0 + w;    // wave w finalizes row r0+w
        if (n < N_NODES) {
            float v = (part[w][0][j] + part[w][1][j] + part[w][2][j] + part[w][3][j]) * norm_out[n];
            h1[n * D_H + j] = v;
        }
    }
}

// ---------------- agg1: g[n][:] = relu(sum_e h1[ssrc[e]][:] * ni + b1) * no ----------------
// wave per node; lane = (dim-quad q = lane&15, edge slot t = lane>>4); float4 gathers.

__global__ void __launch_bounds__(256) agg1_kernel(const int* __restrict__ start,
                                                   const int* __restrict__ ssrc,
                                                   const float* __restrict__ h1,
                                                   const float* __restrict__ norm_in,
                                                   const float* __restrict__ norm_out,
                                                   const float* __restrict__ b1,
                                                   float* __restrict__ g) {
    const int lane = threadIdx.x & 63;
    const int q = lane & 15;
    const int t = lane >> 4;
    const int wave = (int)((blockIdx.x * blockDim.x + threadIdx.x) >> 6);
    const int nwaves = (int)((gridDim.x * blockDim.x) >> 6);

    const float4 bq = *(const float4*)&b1[q * 4];

    for (int n = wave; n < N_NODES; n += nwaves) {
        int beg = __builtin_amdgcn_readfirstlane(start[n]);
        int end = __builtin_amdgcn_readfirstlane(start[n + 1]);
        float4 acc = make_float4(0.f, 0.f, 0.f, 0.f);
        for (int e = beg + t; e < end; e += 4) {
            int s = ssrc[e];
            float4 v = *(const float4*)(h1 + s * D_H + q * 4);
            acc.x += v.x; acc.y += v.y; acc.z += v.z; acc.w += v.w;
        }
        // reduce across edge slots (lane bits 4,5)
        acc.x += __shfl_xor(acc.x, 16); acc.y += __shfl_xor(acc.y, 16);
        acc.z += __shfl_xor(acc.z, 16); acc.w += __shfl_xor(acc.w, 16);
        acc.x += __shfl_xor(acc.x, 32); acc.y += __shfl_xor(acc.y, 32);
        acc.z += __shfl_xor(acc.z, 32); acc.w += __shfl_xor(acc.w, 32);
        if (t == 0) {
            float ni = norm_in[n], no = norm_out[n];
            float4 r;
            r.x = fmaxf(fmaf(acc.x, ni, bq.x), 0.f) * no;
            r.y = fmaxf(fmaf(acc.y, ni, bq.y), 0.f) * no;
            r.z = fmaxf(fmaf(acc.z, ni, bq.z), 0.f) * no;
            r.w = fmaxf(fmaf(acc.w, ni, bq.w), 0.f) * no;
            *(float4*)(g + n * D_H + q * 4) = r;
        }
    }
}

// ---------------- GEMM2: h2[n][j] = dot(g[n,:64], W2[:,j]), padded to 48 cols ----------------

__global__ void __launch_bounds__(256, 4) gemm2_kernel(const float* __restrict__ g,
                                                       const float* __restrict__ W2,
                                                       float* __restrict__ h2) {
    const int j = threadIdx.x & 63;
    const int wave = (int)((blockIdx.x * blockDim.x + threadIdx.x) >> 6);
    const int nwaves = (int)((gridDim.x * blockDim.x) >> 6);

    float wreg[64];
#pragma unroll
    for (int kk = 0; kk < 64; ++kk)
        wreg[kk] = (j < D_O) ? W2[kk * D_O + j] : 0.0f;

    for (int n = wave; n < N_NODES; n += nwaves) {
        int off = __builtin_amdgcn_readfirstlane(n * D_H);
        const float* gp = g + off;
        float acc = 0.0f;
#pragma unroll
        for (int kk = 0; kk < 64; ++kk)
            acc = fmaf(gp[kk], wreg[kk], acc);
        if (j < D_OP)
            h2[n * D_OP + j] = acc;   // cols 40..47 are zeros
    }
}

// ---------------- agg2: out[n][:] = (sum_e h2[ssrc[e]][:]) * ni + b2 ----------------
// lane = (quad q = lane%12 of 48 padded dims, edge slot t = lane/12, t<5 active)

__global__ void __launch_bounds__(256) agg2_kernel(const int* __restrict__ start,
                                                   const int* __restrict__ ssrc,
                                                   const float* __restrict__ h2,
                                                   const float* __restrict__ norm_in,
                                                   const float* __restrict__ b2,
                                                   float* __restrict__ out) {
    const int lane = threadIdx.x & 63;
    const int q = lane % 12;
    const int t = lane / 12;           // 0..5; t==5 (lanes 60-63) idle
    const int wave = (int)((blockIdx.x * blockDim.x + threadIdx.x) >> 6);
    const int nwaves = (int)((gridDim.x * blockDim.x) >> 6);

    for (int n = wave; n < N_NODES; n += nwaves) {
        int beg = __builtin_amdgcn_readfirstlane(start[n]);
        int end = __builtin_amdgcn_readfirstlane(start[n + 1]);
        float4 acc = make_float4(0.f, 0.f, 0.f, 0.f);
        if (t < 5) {
            for (int e = beg + t; e < end; e += 5) {
                int s = ssrc[e];
                float4 v = *(const float4*)(h2 + s * D_OP + q * 4);
                acc.x += v.x; acc.y += v.y; acc.z += v.z; acc.w += v.w;
            }
        }
        // reduce the 5 slot-groups onto t==0 lanes (q preserved: offsets of 12)
        float sx = acc.x, sy = acc.y, sz = acc.z, sw = acc.w;
#pragma unroll
        for (int o = 1; o < 5; ++o) {
            sx += __shfl(acc.x, lane + o * 12, 64);
            sy += __shfl(acc.y, lane + o * 12, 64);
            sz += __shfl(acc.z, lane + o * 12, 64);
            sw += __shfl(acc.w, lane + o * 12, 64);
        }
        if (lane < 10) {   // 10 quads cover the real 40 output dims
            float ni = norm_in[n];
            float4 bq = *(const float4*)&b2[lane * 4];
            float4 r;
            r.x = fmaf(sx, ni, bq.x);
            r.y = fmaf(sy, ni, bq.y);
            r.z = fmaf(sz, ni, bq.z);
            r.w = fmaf(sw, ni, bq.w);
            *(float4*)(out + (size_t)n * D_O + lane * 4) = r;
        }
    }
}

// ----------------------------------------------------------------------------

static inline char* alignup(char* p, size_t a) {
    return (char*)(((uintptr_t)p + a - 1) & ~(uintptr_t)(a - 1));
}

extern "C" void kernel_launch(void* const* d_in, const int* in_sizes, int n_in,
                              void* d_out, int out_size, void* d_ws, size_t ws_size,
                              hipStream_t stream) {
    const float* feat = (const float*)d_in[0];
    const int*   src  = (const int*)d_in[1];
    const int*   dst  = (const int*)d_in[2];
    const float* W1   = (const float*)d_in[3];
    const float* b1   = (const float*)d_in[4];
    const float* W2   = (const float*)d_in[5];
    const float* b2   = (const float*)d_in[6];
    float* out = (float*)d_out;

    char* p = alignup((char*)d_ws, 256);
    int*   cnt_out  = (int*)p;    p = alignup(p + N_NODES * 4, 256);
    int*   cnt_in   = (int*)p;    p = alignup(p + N_NODES * 4, 256);
    int*   cursor   = (int*)p;    p = alignup(p + N_NODES * 4, 256);
    int*   start    = (int*)p;    p = alignup(p + (N_NODES + 1) * 4, 256);
    int*   blocksum = (int*)p;    p = alignup(p + 256 * 4, 256);
    float* norm_out = (float*)p;  p = alignup(p + N_NODES * 4, 256);
    float* norm_in  = (float*)p;  p = alignup(p + N_NODES * 4, 256);
    int*   ssrc     = (int*)p;    p = alignup(p + N_EDGES * 4, 256);
    float* h1       = (float*)p;  p = alignup(p + (size_t)N_NODES * D_H * 4, 256);
    float* g        = (float*)p;  p = alignup(p + (size_t)N_NODES * D_H * 4, 256);
    float* h2       = h1;         // h1 dead after agg1; N*48 <= N*64

    // zero cnt_out..cursor (covers the three counter buffers incl. padding)
    hipMemsetAsync(cnt_out, 0, (size_t)((char*)start - (char*)cnt_out), stream);

    hist_kernel<<<(N_EDGES + 255) / 256, 256, 0, stream>>>(src, dst, cnt_out, cnt_in);
    norm_kernel<<<(N_NODES + 255) / 256, 256, 0, stream>>>(cnt_out, cnt_in, norm_out, norm_in);

    scan1_kernel<<<SCAN_NB, 256, 0, stream>>>(cnt_in, start, blocksum);
    scan2_kernel<<<1, 256, 0, stream>>>(blocksum);
    scan3_kernel<<<SCAN_NB, 256, 0, stream>>>(start, blocksum);
    scatter_kernel<<<(N_EDGES + 255) / 256, 256, 0, stream>>>(src, dst, start, cursor, ssrc);

    gemm1_kernel<<<1024, 256, 0, stream>>>(feat, W1, norm_out, h1);
    agg1_kernel<<<1024, 256, 0, stream>>>(start, ssrc, h1, norm_in, norm_out, b1, g);

    gemm2_kernel<<<512, 256, 0, stream>>>(g, W2, h2);
    agg2_kernel<<<1024, 256, 0, stream>>>(start, ssrc, h2, norm_in, b2, out);
}

// Round 4
// 270.630 us; speedup vs baseline: 1.7984x; 1.0480x over previous
//
#include <hip/hip_runtime.h>
#include <stdint.h>

#define N_NODES 50000
#define N_EDGES 800000
#define D_IN    256
#define D_H     64
#define D_O     40
#define D_OP    48   // h2 padded row stride

// ---------------- degree histogram (int) ----------------

__global__ void hist_kernel(const int* __restrict__ src, const int* __restrict__ dst,
                            int* __restrict__ cnt_out, int* __restrict__ cnt_in) {
    int e = blockIdx.x * blockDim.x + threadIdx.x;
    if (e < N_EDGES) {
        atomicAdd(&cnt_out[src[e]], 1);
        atomicAdd(&cnt_in[dst[e]], 1);
    }
}

__global__ void norm_kernel(const int* __restrict__ cnt_out, const int* __restrict__ cnt_in,
                            float* __restrict__ norm_out, float* __restrict__ norm_in) {
    int i = blockIdx.x * blockDim.x + threadIdx.x;
    if (i < N_NODES) {
        norm_out[i] = rsqrtf(fmaxf((float)cnt_out[i], 1.0f));
        norm_in[i]  = rsqrtf(fmaxf((float)cnt_in[i], 1.0f));
    }
}

// ---------------- exclusive scan of cnt_in -> start[] ----------------

#define SCAN_NB ((N_NODES + 255) / 256)   // 196

__global__ void scan1_kernel(const int* __restrict__ cnt, int* __restrict__ start,
                             int* __restrict__ blocksum) {
    __shared__ int tmp[256];
    int i = blockIdx.x * 256 + threadIdx.x;
    int v = (i < N_NODES) ? cnt[i] : 0;
    tmp[threadIdx.x] = v;
    __syncthreads();
    for (int off = 1; off < 256; off <<= 1) {
        int t = (threadIdx.x >= off) ? tmp[threadIdx.x - off] : 0;
        __syncthreads();
        tmp[threadIdx.x] += t;
        __syncthreads();
    }
    if (i < N_NODES) start[i] = tmp[threadIdx.x] - v;
    if (threadIdx.x == 255) blocksum[blockIdx.x] = tmp[255];
}

__global__ void scan2_kernel(int* __restrict__ blocksum) {
    __shared__ int tmp[256];
    int v = (threadIdx.x < SCAN_NB) ? blocksum[threadIdx.x] : 0;
    tmp[threadIdx.x] = v;
    __syncthreads();
    for (int off = 1; off < 256; off <<= 1) {
        int t = (threadIdx.x >= off) ? tmp[threadIdx.x - off] : 0;
        __syncthreads();
        tmp[threadIdx.x] += t;
        __syncthreads();
    }
    blocksum[threadIdx.x] = tmp[threadIdx.x] - v;
}

__global__ void scan3_kernel(int* __restrict__ start, const int* __restrict__ blocksum) {
    int i = blockIdx.x * 256 + threadIdx.x;
    if (i < N_NODES) start[i] += blocksum[i >> 8];
    if (i == 0) start[N_NODES] = N_EDGES;
}

// ---------------- scatter edges into CSR order ----------------

__global__ void scatter_kernel(const int* __restrict__ src, const int* __restrict__ dst,
                               const int* __restrict__ start, int* __restrict__ cursor,
                               int* __restrict__ ssrc) {
    int e = blockIdx.x * blockDim.x + threadIdx.x;
    if (e < N_EDGES) {
        int d = dst[e];
        int pos = start[d] + atomicAdd(&cursor[d], 1);
        ssrc[pos] = src[e];
    }
}

// ---------------- W2 zero-padded to [64][48] ----------------

__global__ void padw2_kernel(const float* __restrict__ W2, float* __restrict__ W2p) {
    int i = blockIdx.x * blockDim.x + threadIdx.x;
    if (i < D_H * D_OP) {
        int k = i / D_OP, j = i - k * D_OP;
        W2p[i] = (j < D_O) ? W2[k * D_O + j] : 0.0f;
    }
}

// ---------------- GEMM1: h1[n][j] = norm_out[n] * dot(feat[n,:], W1[:,j]) ----------------
// LDS-tiled: 64 rows/block, K-chunks of 32 staged with padded stride 33.
// W1 read via wave-uniform scalar loads; per-thread acc[16] (4 waves x 16 cols).

#define G1S 33

__global__ void __launch_bounds__(256, 8) gemm1_kernel(const float* __restrict__ feat,
                                                       const float* __restrict__ W1,
                                                       const float* __restrict__ norm_out,
                                                       float* __restrict__ h1) {
    __shared__ float tile[64 * G1S];   // 8448 B
    const int tid = threadIdx.x;
    const int lane = tid & 63;
    const int cbase = __builtin_amdgcn_readfirstlane((tid >> 6) * 16);
    const int n0 = blockIdx.x * 64;

    float acc[16];
#pragma unroll
    for (int c = 0; c < 16; ++c) acc[c] = 0.0f;

    for (int k0 = 0; k0 < D_IN; k0 += 32) {
        __syncthreads();   // tile free from previous compute
#pragma unroll
        for (int it = 0; it < 2; ++it) {
            int idx = it * 256 + tid;           // 0..511
            int row = idx >> 3;
            int q = idx & 7;
            int nr = n0 + row; if (nr >= N_NODES) nr = N_NODES - 1;
            float4 v = *(const float4*)(feat + nr * D_IN + k0 + q * 4);
            float* dp = &tile[row * G1S + q * 4];
            dp[0] = v.x; dp[1] = v.y; dp[2] = v.z; dp[3] = v.w;
        }
        __syncthreads();
        const float* wp = W1 + k0 * D_H + cbase;   // wave-uniform
#pragma unroll
        for (int kk = 0; kk < 32; ++kk) {
            float f = tile[lane * G1S + kk];
#pragma unroll
            for (int c = 0; c < 16; ++c)
                acc[c] = fmaf(f, wp[kk * D_H + c], acc[c]);
        }
    }
    int n = n0 + lane;
    if (n < N_NODES) {
        float no = norm_out[n];
        float* hp = h1 + n * D_H + cbase;
#pragma unroll
        for (int c0 = 0; c0 < 16; c0 += 4) {
            float4 r = make_float4(acc[c0] * no, acc[c0 + 1] * no,
                                   acc[c0 + 2] * no, acc[c0 + 3] * no);
            *(float4*)(hp + c0) = r;
        }
    }
}

// ---------------- agg1: g[n][:] = relu(sum_e h1[ssrc[e]][:] * ni + b1) * no ----------------

__global__ void __launch_bounds__(256) agg1_kernel(const int* __restrict__ start,
                                                   const int* __restrict__ ssrc,
                                                   const float* __restrict__ h1,
                                                   const float* __restrict__ norm_in,
                                                   const float* __restrict__ norm_out,
                                                   const float* __restrict__ b1,
                                                   float* __restrict__ g) {
    const int lane = threadIdx.x & 63;
    const int q = lane & 15;
    const int t = lane >> 4;
    const int wave = (int)((blockIdx.x * blockDim.x + threadIdx.x) >> 6);
    const int nwaves = (int)((gridDim.x * blockDim.x) >> 6);

    const float4 bq = *(const float4*)&b1[q * 4];

    for (int n = wave; n < N_NODES; n += nwaves) {
        int beg = __builtin_amdgcn_readfirstlane(start[n]);
        int end = __builtin_amdgcn_readfirstlane(start[n + 1]);
        float4 acc = make_float4(0.f, 0.f, 0.f, 0.f);
        for (int e = beg + t; e < end; e += 4) {
            int s = ssrc[e];
            float4 v = *(const float4*)(h1 + s * D_H + q * 4);
            acc.x += v.x; acc.y += v.y; acc.z += v.z; acc.w += v.w;
        }
        acc.x += __shfl_xor(acc.x, 16); acc.y += __shfl_xor(acc.y, 16);
        acc.z += __shfl_xor(acc.z, 16); acc.w += __shfl_xor(acc.w, 16);
        acc.x += __shfl_xor(acc.x, 32); acc.y += __shfl_xor(acc.y, 32);
        acc.z += __shfl_xor(acc.z, 32); acc.w += __shfl_xor(acc.w, 32);
        if (t == 0) {
            float ni = norm_in[n], no = norm_out[n];
            float4 r;
            r.x = fmaxf(fmaf(acc.x, ni, bq.x), 0.f) * no;
            r.y = fmaxf(fmaf(acc.y, ni, bq.y), 0.f) * no;
            r.z = fmaxf(fmaf(acc.z, ni, bq.z), 0.f) * no;
            r.w = fmaxf(fmaf(acc.w, ni, bq.w), 0.f) * no;
            *(float4*)(g + n * D_H + q * 4) = r;
        }
    }
}

// ---------------- GEMM2: h2[n][0:48] = dot(g[n,:64], W2p[:,0:48]) ----------------
// Same tiled structure; 4 waves x 12 cols, acc[12], K=64 in 2 chunks.

__global__ void __launch_bounds__(256, 8) gemm2_kernel(const float* __restrict__ g,
                                                       const float* __restrict__ W2p,
                                                       float* __restrict__ h2) {
    __shared__ float tile[64 * G1S];
    const int tid = threadIdx.x;
    const int lane = tid & 63;
    const int cbase = __builtin_amdgcn_readfirstlane((tid >> 6) * 12);
    const int n0 = blockIdx.x * 64;

    float acc[12];
#pragma unroll
    for (int c = 0; c < 12; ++c) acc[c] = 0.0f;

    for (int k0 = 0; k0 < D_H; k0 += 32) {
        __syncthreads();
#pragma unroll
        for (int it = 0; it < 2; ++it) {
            int idx = it * 256 + tid;
            int row = idx >> 3;
            int q = idx & 7;
            int nr = n0 + row; if (nr >= N_NODES) nr = N_NODES - 1;
            float4 v = *(const float4*)(g + nr * D_H + k0 + q * 4);
            float* dp = &tile[row * G1S + q * 4];
            dp[0] = v.x; dp[1] = v.y; dp[2] = v.z; dp[3] = v.w;
        }
        __syncthreads();
        const float* wp = W2p + k0 * D_OP + cbase;   // wave-uniform
#pragma unroll
        for (int kk = 0; kk < 32; ++kk) {
            float f = tile[lane * G1S + kk];
#pragma unroll
            for (int c = 0; c < 12; ++c)
                acc[c] = fmaf(f, wp[kk * D_OP + c], acc[c]);
        }
    }
    int n = n0 + lane;
    if (n < N_NODES) {
        float* hp = h2 + n * D_OP + cbase;
#pragma unroll
        for (int c0 = 0; c0 < 12; c0 += 4) {
            float4 r = make_float4(acc[c0], acc[c0 + 1], acc[c0 + 2], acc[c0 + 3]);
            *(float4*)(hp + c0) = r;
        }
    }
}

// ---------------- agg2: out[n][:] = (sum_e h2[ssrc[e]][:]) * ni + b2 ----------------

__global__ void __launch_bounds__(256) agg2_kernel(const int* __restrict__ start,
                                                   const int* __restrict__ ssrc,
                                                   const float* __restrict__ h2,
                                                   const float* __restrict__ norm_in,
                                                   const float* __restrict__ b2,
                                                   float* __restrict__ out) {
    const int lane = threadIdx.x & 63;
    const int q = lane % 12;
    const int t = lane / 12;           // 0..5; t==5 idle
    const int wave = (int)((blockIdx.x * blockDim.x + threadIdx.x) >> 6);
    const int nwaves = (int)((gridDim.x * blockDim.x) >> 6);

    for (int n = wave; n < N_NODES; n += nwaves) {
        int beg = __builtin_amdgcn_readfirstlane(start[n]);
        int end = __builtin_amdgcn_readfirstlane(start[n + 1]);
        float4 acc = make_float4(0.f, 0.f, 0.f, 0.f);
        if (t < 5) {
            for (int e = beg + t; e < end; e += 5) {
                int s = ssrc[e];
                float4 v = *(const float4*)(h2 + s * D_OP + q * 4);
                acc.x += v.x; acc.y += v.y; acc.z += v.z; acc.w += v.w;
            }
        }
        float sx = acc.x, sy = acc.y, sz = acc.z, sw = acc.w;
#pragma unroll
        for (int o = 1; o < 5; ++o) {
            sx += __shfl(acc.x, lane + o * 12, 64);
            sy += __shfl(acc.y, lane + o * 12, 64);
            sz += __shfl(acc.z, lane + o * 12, 64);
            sw += __shfl(acc.w, lane + o * 12, 64);
        }
        if (lane < 10) {
            float ni = norm_in[n];
            float4 bq = *(const float4*)&b2[lane * 4];
            float4 r;
            r.x = fmaf(sx, ni, bq.x);
            r.y = fmaf(sy, ni, bq.y);
            r.z = fmaf(sz, ni, bq.z);
            r.w = fmaf(sw, ni, bq.w);
            *(float4*)(out + (size_t)n * D_O + lane * 4) = r;
        }
    }
}

// ----------------------------------------------------------------------------

static inline char* alignup(char* p, size_t a) {
    return (char*)(((uintptr_t)p + a - 1) & ~(uintptr_t)(a - 1));
}

extern "C" void kernel_launch(void* const* d_in, const int* in_sizes, int n_in,
                              void* d_out, int out_size, void* d_ws, size_t ws_size,
                              hipStream_t stream) {
    const float* feat = (const float*)d_in[0];
    const int*   src  = (const int*)d_in[1];
    const int*   dst  = (const int*)d_in[2];
    const float* W1   = (const float*)d_in[3];
    const float* b1   = (const float*)d_in[4];
    const float* W2   = (const float*)d_in[5];
    const float* b2   = (const float*)d_in[6];
    float* out = (float*)d_out;

    char* p = alignup((char*)d_ws, 256);
    int*   cnt_out  = (int*)p;    p = alignup(p + N_NODES * 4, 256);
    int*   cnt_in   = (int*)p;    p = alignup(p + N_NODES * 4, 256);
    int*   cursor   = (int*)p;    p = alignup(p + N_NODES * 4, 256);
    int*   start    = (int*)p;    p = alignup(p + (N_NODES + 1) * 4, 256);
    int*   blocksum = (int*)p;    p = alignup(p + 256 * 4, 256);
    float* norm_out = (float*)p;  p = alignup(p + N_NODES * 4, 256);
    float* norm_in  = (float*)p;  p = alignup(p + N_NODES * 4, 256);
    float* W2p      = (float*)p;  p = alignup(p + D_H * D_OP * 4, 256);
    int*   ssrc     = (int*)p;    p = alignup(p + N_EDGES * 4, 256);
    float* h1       = (float*)p;  p = alignup(p + (size_t)N_NODES * D_H * 4, 256);
    float* g        = (float*)p;  p = alignup(p + (size_t)N_NODES * D_H * 4, 256);
    float* h2       = h1;         // h1 dead after agg1; N*48 <= N*64

    hipMemsetAsync(cnt_out, 0, (size_t)((char*)start - (char*)cnt_out), stream);

    hist_kernel<<<(N_EDGES + 255) / 256, 256, 0, stream>>>(src, dst, cnt_out, cnt_in);
    norm_kernel<<<(N_NODES + 255) / 256, 256, 0, stream>>>(cnt_out, cnt_in, norm_out, norm_in);

    scan1_kernel<<<SCAN_NB, 256, 0, stream>>>(cnt_in, start, blocksum);
    scan2_kernel<<<1, 256, 0, stream>>>(blocksum);
    scan3_kernel<<<SCAN_NB, 256, 0, stream>>>(start, blocksum);
    scatter_kernel<<<(N_EDGES + 255) / 256, 256, 0, stream>>>(src, dst, start, cursor, ssrc);
    padw2_kernel<<<(D_H * D_OP + 255) / 256, 256, 0, stream>>>(W2, W2p);

    gemm1_kernel<<<(N_NODES + 63) / 64, 256, 0, stream>>>(feat, W1, norm_out, h1);
    agg1_kernel<<<1024, 256, 0, stream>>>(start, ssrc, h1, norm_in, norm_out, b1, g);

    gemm2_kernel<<<(N_NODES + 63) / 64, 256, 0, stream>>>(g, W2p, h2);
    agg2_kernel<<<1024, 256, 0, stream>>>(start, ssrc, h2, norm_in, b2, out);
}